// Round 6
// baseline (207.211 us; speedup 1.0000x reference)
//
#include <hip/hip_runtime.h>
#include <hip/hip_cooperative_groups.h>

namespace cg = cooperative_groups;

typedef short bf16x8 __attribute__((ext_vector_type(8)));
typedef float f32x16 __attribute__((ext_vector_type(16)));

#define BIG_F 1e10f
constexpr int B = 16;
constexpr int N = 4096;
constexpr int ROWS = 128;         // x-rows per job
constexpr int COLS = 512;         // y-cols per B-slice
constexpr int NRB = N / ROWS;     // 32
constexpr int NCB = N / COLS;     // 8
constexpr int VBLOCKS = 1024;     // virtual blocks: (b,cb,sub), 4 rb-jobs each

// truncating bf16 hi/lo split: v ~= hi + lo
__device__ __forceinline__ void split(float v, unsigned& h, unsigned& l) {
    unsigned hb = __float_as_uint(v) & 0xFFFF0000u;
    h = hb >> 16;
    float r = v - __uint_as_float(hb);
    l = __float_as_uint(r) >> 16;
}

__device__ __forceinline__ float min3f(float a, float b, float c) {
    return fminf(fminf(a, b), c);   // fuses to v_min3_f32
}

__device__ __forceinline__ float vmin16(f32x16 C) {
    float u0 = min3f(C[0], C[1], C[2]);
    float u1 = min3f(C[3], C[4], C[5]);
    float u2 = min3f(C[6], C[7], C[8]);
    float u3 = min3f(C[9], C[10], C[11]);
    float u4 = min3f(C[12], C[13], C[14]);
    return min3f(min3f(u0, u1, u2), fminf(u3, u4), C[15]);
}

// Fused cooperative kernel: pack -> grid.sync -> chamfer -> grid.sync -> finalize.
// MFMA layout (mfma_f32_32x32x16_bf16, all 16 K-slots):
//   A_k(n) = [ah0..2, ah0..2, al0..2, al0..2, xxh, xxl, 1, 1]   (ah+al = -2x)
//   B_k(m) = [yh0..2, yl0..2, yh0..2, yl0..2, 1, 1, qh, ql]     (qh+ql = yy)
// Each virtual block stages ONE B-slice (b,cb) and runs 4 rb-jobs against it.
// Col partials go per-(wave,half) to colbuf[8][*] (no in-loop cross-half shfl;
// R5 paid 2x ~120cy ds-pipe shfl per iter on the critical path).
__global__ __launch_bounds__(256, 4) void chamfer_all(
    const float* __restrict__ x, const float* __restrict__ y,
    const int* __restrict__ mask,
    uint4* __restrict__ Apg,       // [B][2][N] A fragments
    uint4* __restrict__ Bpg,       // [B][2][N] B fragments
    float* __restrict__ rowpart,   // [B][NCB][N] row-min partials (over 512 cols)
    float* __restrict__ colpart,   // [B][NRB][N] col-min partials (over 128 rows)
    float* __restrict__ out)
{
    cg::grid_group grid = cg::this_grid();
    const int blk = blockIdx.x;
    const int t   = threadIdx.x;

    __shared__ __align__(16) unsigned short Bpack[2][COLS][8];   // 16 KB
    __shared__ float colbuf[8][COLS];                            // 16 KB
    __shared__ float rs[4];
    __shared__ int   rc[4];

    // ================= phase 1: pack (each point once) =================
    for (int idx = blk * 256 + t; idx < B * N; idx += gridDim.x * 256) {
        if (idx == 0) out[0] = 0.0f;
        const int pb = idx >> 12;          // batch
        const int pt = idx & (N - 1);
        const float* xb = x + (size_t)pb * 3 * N;
        const float* yb = y + (size_t)pb * 3 * N;
        const float madd = mask[pb * N + pt] ? 0.0f : BIG_F;
        {   // x -> A fragments
            float x0 = xb[pt], x1 = xb[N + pt], x2 = xb[2 * N + pt];
            float xx = fmaf(x2, x2, fmaf(x1, x1, x0 * x0)) + madd;
            unsigned h0, l0, h1, l1, h2, l2, xh, xl;
            split(-2.0f * x0, h0, l0);
            split(-2.0f * x1, h1, l1);
            split(-2.0f * x2, h2, l2);
            split(xx, xh, xl);
            uint4 w0 = { h0 | (h1 << 16), h2 | (h0 << 16), h1 | (h2 << 16), l0 | (l1 << 16) };
            uint4 w1 = { l2 | (l0 << 16), l1 | (l2 << 16), xh | (xl << 16), 0x3F803F80u };
            Apg[(size_t)(pb * 2 + 0) * N + pt] = w0;
            Apg[(size_t)(pb * 2 + 1) * N + pt] = w1;
        }
        {   // y -> B fragments
            float y0 = yb[pt], y1 = yb[N + pt], y2 = yb[2 * N + pt];
            float yy = fmaf(y2, y2, fmaf(y1, y1, y0 * y0)) + madd;
            unsigned h0, l0, h1, l1, h2, l2, qh, ql;
            split(y0, h0, l0);
            split(y1, h1, l1);
            split(y2, h2, l2);
            split(yy, qh, ql);
            unsigned u0 = h0 | (h1 << 16);
            unsigned u1 = h2 | (l0 << 16);
            unsigned u2 = l1 | (l2 << 16);
            uint4 w0 = { u0, u1, u2, u0 };
            uint4 w1 = { u1, u2, 0x3F803F80u, qh | (ql << 16) };
            Bpg[(size_t)(pb * 2 + 0) * N + pt] = w0;
            Bpg[(size_t)(pb * 2 + 1) * N + pt] = w1;
        }
    }
    grid.sync();

    // ================= phase 2: chamfer tiles =================
    const int w    = t >> 6;    // wave 0..3, owns rows w*32..w*32+31
    const int L    = t & 63;
    const int half = L >> 5;    // k-half 0/1
    const int lc   = L & 31;    // row/col within 32-tile

    const f32x16 z16 = {0.f,0.f,0.f,0.f,0.f,0.f,0.f,0.f,
                        0.f,0.f,0.f,0.f,0.f,0.f,0.f,0.f};

    for (int vb = blk; vb < VBLOCKS; vb += gridDim.x) {
        const int grp = vb >> 3;          // 128 groups = (b, cb)
        const int b   = grp >> 3;
        const int cb  = grp & 7;
        const int sub = vb & 7;           // rb = sub*4 + jj

        // ---- stage B slice once for 4 jobs: pure copy, 4 uint4/thread ----
        uint4* Bl = (uint4*)&Bpack[0][0][0];
        const uint4* Bg = Bpg + (size_t)b * 2 * N + cb * COLS;
#pragma unroll
        for (int k = 0; k < 4; ++k) {
            int i = t + k * 256;                  // i>>9 = khalf, i&511 = pos
            Bl[i] = Bg[(size_t)(i >> 9) * N + (i & 511)];
        }
        __syncthreads();

        const unsigned short* Bb = &Bpack[half][lc][0];

#pragma unroll 1
        for (int jj = 0; jj < 4; ++jj) {
            const int rb = sub * 4 + jj;
            // A fragment straight to regs (one 16B fragment per lane)
            uint4 av = Apg[(size_t)(b * 2 + half) * N + rb * ROWS + w * 32 + lc];
            bf16x8 afr = *(bf16x8*)&av;

            float rm[16];
#pragma unroll
            for (int r = 0; r < 16; ++r) rm[r] = 1e30f;

#pragma unroll 1
            for (int p = 0; p < 8; ++p) {          // 8 col-pairs of 32 = 512 cols
                bf16x8 bf0 = *(const bf16x8*)(Bb + p * 512);
                bf16x8 bf1 = *(const bf16x8*)(Bb + p * 512 + 256);
                f32x16 C0 = __builtin_amdgcn_mfma_f32_32x32x16_bf16(afr, bf0, z16, 0, 0, 0);
                f32x16 C1 = __builtin_amdgcn_mfma_f32_32x32x16_bf16(afr, bf1, z16, 0, 0, 0);
                // row-mins: C[r] is row w*32+(r&3)+8*(r>>2)+4*half, col p*64(+32)+lc
#pragma unroll
                for (int r = 0; r < 16; ++r) rm[r] = min3f(rm[r], C0[r], C1[r]);
                // col partial over this half's 16 rows; cross-half folded in epilogue
                colbuf[w * 2 + half][p * 64 + lc]      = vmin16(C0);
                colbuf[w * 2 + half][p * 64 + 32 + lc] = vmin16(C1);
            }

            // finish row-mins across the 32 col-lanes (stays within half)
#pragma unroll
            for (int off = 1; off <= 16; off <<= 1)
#pragma unroll
                for (int r = 0; r < 16; ++r)
                    rm[r] = fminf(rm[r], __shfl_xor(rm[r], off));
            if (lc == 0) {
                float* rp = rowpart + ((size_t)b * NCB + cb) * N + rb * ROWS
                          + w * 32 + half * 4;
#pragma unroll
                for (int r = 0; r < 16; ++r)
                    rp[(r & 3) + 8 * (r >> 2)] = rm[r];
            }

            __syncthreads();   // colbuf complete
            // combine 8 (wave,half) slabs -> col partial over 128 rows
            float* cpo = colpart + ((size_t)b * NRB + rb) * N + cb * COLS;
#pragma unroll
            for (int i = 0; i < 2; ++i) {
                int c = t + i * 256;
                float v = colbuf[0][c];
#pragma unroll
                for (int s = 1; s < 8; ++s) v = fminf(v, colbuf[s][c]);
                cpo[c] = v;
            }
            __syncthreads();   // colbuf consumed (next job / next stage reuses)
        }
    }
    grid.sync();

    // ================= phase 3: finalize (64 blocks) =================
    if (blk < 64) {
        const int b = blk & 15;
        const int q = blk >> 4;   // quarter 0..3
        const int* mrow = mask + b * N;

        int cnt = 0;
        for (int i = t; i < N / 4; i += 256) {
            int4 mk = ((const int4*)mrow)[i];
            cnt += mk.x + mk.y + mk.z + mk.w;
        }

        const int p0 = q * 1024 + t * 4;

        const float* cp = colpart + (size_t)b * NRB * N + p0;
        float4 mn = *(const float4*)cp;
#pragma unroll 4
        for (int pb = 1; pb < NRB; ++pb) {
            float4 v = *(const float4*)(cp + (size_t)pb * N);
            mn.x = fminf(mn.x, v.x); mn.y = fminf(mn.y, v.y);
            mn.z = fminf(mn.z, v.z); mn.w = fminf(mn.w, v.w);
        }
        const float* rp = rowpart + (size_t)b * NCB * N + p0;
        float4 rn = *(const float4*)rp;
#pragma unroll
        for (int pb = 1; pb < NCB; ++pb) {
            float4 v = *(const float4*)(rp + (size_t)pb * N);
            rn.x = fminf(rn.x, v.x); rn.y = fminf(rn.y, v.y);
            rn.z = fminf(rn.z, v.z); rn.w = fminf(rn.w, v.w);
        }
        int4 mk = *(const int4*)(mrow + p0);
        float s = (mk.x ? (mn.x + rn.x) : 0.f) + (mk.y ? (mn.y + rn.y) : 0.f)
                + (mk.z ? (mn.z + rn.z) : 0.f) + (mk.w ? (mn.w + rn.w) : 0.f);

        for (int off = 32; off > 0; off >>= 1) {
            s   += __shfl_down(s, off);
            cnt += __shfl_down(cnt, off);
        }
        const int wv = t >> 6;
        if ((t & 63) == 0) { rs[wv] = s; rc[wv] = cnt; }
        __syncthreads();
        if (t == 0) {
            float S = rs[0] + rs[1] + rs[2] + rs[3];
            float C = (float)(rc[0] + rc[1] + rc[2] + rc[3]);
            atomicAdd(out, (S / C) * (1.0f / 16.0f));
        }
    }
}

extern "C" void kernel_launch(void* const* d_in, const int* in_sizes, int n_in,
                              void* d_out, int out_size, void* d_ws, size_t ws_size,
                              hipStream_t stream) {
    const float* x    = (const float*)d_in[0];
    const float* y    = (const float*)d_in[1];
    const int*   mask = (const int*)d_in[2];

    uint4* Apg     = (uint4*)d_ws;                        // 2 MB
    uint4* Bpg     = Apg + (size_t)B * 2 * N;             // 2 MB
    float* rowpart = (float*)(Bpg + (size_t)B * 2 * N);   // 2 MB
    float* colpart = rowpart + (size_t)B * NCB * N;       // 8 MB
    float* outp    = (float*)d_out;

    // grid must not exceed co-residency for cooperative launch
    static int grid = 0;
    if (grid == 0) {
        int occ = 0;
        if (hipOccupancyMaxActiveBlocksPerMultiprocessor(&occ, chamfer_all, 256, 0)
                != hipSuccess || occ < 1)
            occ = 2;                                      // safe floor (64KB LDS)
        grid = occ * 256;                                 // 256 CUs on MI355X
        if (grid > VBLOCKS) grid = VBLOCKS;
    }

    void* args[] = { (void*)&x, (void*)&y, (void*)&mask, (void*)&Apg, (void*)&Bpg,
                     (void*)&rowpart, (void*)&colpart, (void*)&outp };
    hipLaunchCooperativeKernel(chamfer_all, dim3(grid), dim3(256), args, 0, stream);
}